// Round 1
// baseline (742.575 us; speedup 1.0000x reference)
//
#include <hip/hip_runtime.h>
#include <cstdint>
#include <cstddef>

#define M_DIM 8192
#define N_DIM 4096
#define K_DIM 4096

#define BM 128
#define BN 128
#define BK 64

using f32x4 = __attribute__((ext_vector_type(4))) float;

// ---------------- fp8 quantize (fp32 -> OCP e4m3fn, RNE via HW cvt) ----------
__device__ __forceinline__ uint32_t pack4_fp8(float a, float b, float c, float d) {
    int v = 0;
    v = __builtin_amdgcn_cvt_pk_fp8_f32(a, b, v, false);  // bytes 0,1
    v = __builtin_amdgcn_cvt_pk_fp8_f32(c, d, v, true);   // bytes 2,3
    return (uint32_t)v;
}

__global__ void quant_fp8(const float* __restrict__ in, uint32_t* __restrict__ out, int n4) {
    int stride = gridDim.x * blockDim.x;
    for (int i = blockIdx.x * blockDim.x + threadIdx.x; i < n4; i += stride) {
        float4 v = reinterpret_cast<const float4*>(in)[i];
        out[i] = pack4_fp8(v.x, v.y, v.z, v.w);
    }
}

// ---------------- fp8 GEMM: C[m][n] = sum_k A[m][k] * B[n][k] ----------------
__device__ __forceinline__ void async16(const void* g, void* l) {
    __builtin_amdgcn_global_load_lds(
        (const __attribute__((address_space(1))) void*)g,
        (__attribute__((address_space(3))) void*)l,
        16, 0, 0);
}

__global__ __launch_bounds__(256) void gemm_fp8(
    const uint8_t* __restrict__ A,   // [M][K] fp8
    const uint8_t* __restrict__ B,   // [N][K] fp8
    float* __restrict__ C) {         // [M][N] fp32
    __shared__ __align__(16) uint8_t sA[BM][BK];
    __shared__ __align__(16) uint8_t sB[BN][BK];

    const int nbn = N_DIM / BN;                  // 32
    const int nwg = (M_DIM / BM) * nbn;          // 2048 (divisible by 8)
    int bid = blockIdx.x;
    int swz = (bid & 7) * (nwg >> 3) + (bid >> 3);   // bijective XCD swizzle
    int bm = (swz / nbn) * BM;
    int bn = (swz % nbn) * BN;

    int tid  = threadIdx.x;
    int lane = tid & 63;
    int wr = (tid >> 7) & 1;   // wave row (2x2 wave grid)
    int wc = (tid >> 6) & 1;   // wave col

    // staging geometry: 256 thr x 16B = 4KB per issue; tile = 8KB -> 2 issues
    int sr = tid >> 2;             // row 0..63 within half-tile
    int sc = (tid & 3) << 4;       // col {0,16,32,48}

    const uint8_t* ga0 = A + (size_t)(bm + sr) * K_DIM + sc;
    const uint8_t* gb0 = B + (size_t)(bn + sr) * K_DIM + sc;
    uint8_t* la = &sA[0][0] + tid * 16;   // linear LDS dest (wave-uniform + lane*16)
    uint8_t* lb = &sB[0][0] + tid * 16;

    int frow = lane & 15;            // fragment row/col within 16
    int kb   = (lane >> 4) << 3;     // k byte offset within 32-slice

    f32x4 acc[4][4] = {};

    for (int kt = 0; kt < K_DIM; kt += BK) {
        async16(ga0 + kt,                        la);
        async16(ga0 + kt + (size_t)64 * K_DIM,   la + 4096);
        async16(gb0 + kt,                        lb);
        async16(gb0 + kt + (size_t)64 * K_DIM,   lb + 4096);
        __syncthreads();   // compiler drains vmcnt(0) before s_barrier

#pragma unroll
        for (int ks = 0; ks < 2; ++ks) {
            long aF[4], bF[4];
#pragma unroll
            for (int m = 0; m < 4; ++m)
                aF[m] = *(const long*)&sA[wr * 64 + m * 16 + frow][ks * 32 + kb];
#pragma unroll
            for (int n = 0; n < 4; ++n)
                bF[n] = *(const long*)&sB[wc * 64 + n * 16 + frow][ks * 32 + kb];
#pragma unroll
            for (int m = 0; m < 4; ++m)
#pragma unroll
                for (int n = 0; n < 4; ++n)
                    acc[m][n] = __builtin_amdgcn_mfma_f32_16x16x32_fp8_fp8(
                        aF[m], bF[n], acc[m][n], 0, 0, 0);
        }
        __syncthreads();
    }

    // C/D layout (dtype-independent, m89/m91-verified): col=lane&15, row=(lane>>4)*4+r
    int cr = bm + wr * 64 + ((lane >> 4) << 2);
    int cc = bn + wc * 64 + (lane & 15);
#pragma unroll
    for (int m = 0; m < 4; ++m)
#pragma unroll
        for (int n = 0; n < 4; ++n)
#pragma unroll
            for (int r = 0; r < 4; ++r)
                C[(size_t)(cr + m * 16 + r) * N_DIM + cc + n * 16] = acc[m][n][r];
}

extern "C" void kernel_launch(void* const* d_in, const int* in_sizes, int n_in,
                              void* d_out, int out_size, void* d_ws, size_t ws_size,
                              hipStream_t stream) {
    const float* x = (const float*)d_in[0];   // [M, K] fp32
    const float* w = (const float*)d_in[1];   // [N, K] fp32
    float* out = (float*)d_out;               // [M, N] fp32

    uint8_t* xq = (uint8_t*)d_ws;                       // M*K fp8
    uint8_t* wq = xq + (size_t)M_DIM * K_DIM;           // N*K fp8  (total 50.3 MB)

    quant_fp8<<<2048, 256, 0, stream>>>(x, (uint32_t*)xq, M_DIM * K_DIM / 4);
    quant_fp8<<<1024, 256, 0, stream>>>(w, (uint32_t*)wq, N_DIM * K_DIM / 4);
    gemm_fp8<<<(M_DIM / BM) * (N_DIM / BN), 256, 0, stream>>>(xq, wq, out);
}

// Round 7
// 431.919 us; speedup vs baseline: 1.7192x; 1.7192x over previous
//
#include <hip/hip_runtime.h>
#include <cstdint>
#include <cstddef>

#define M_DIM 8192
#define N_DIM 4096
#define K_DIM 4096

#define BM 128
#define BN 128
#define BK 128   // K bytes per tile = one mfma_scale K

using f32x4 = __attribute__((ext_vector_type(4))) float;
using i32x4 = __attribute__((ext_vector_type(4))) int;
using v8i   = __attribute__((ext_vector_type(8))) int;

// ---------------- fp8 quantize (fp32 -> OCP e4m3fn, RNE via HW cvt) ----------
__device__ __forceinline__ uint32_t pack4_fp8(float a, float b, float c, float d) {
    int v = 0;
    v = __builtin_amdgcn_cvt_pk_fp8_f32(a, b, v, false);  // bytes 0,1
    v = __builtin_amdgcn_cvt_pk_fp8_f32(c, d, v, true);   // bytes 2,3
    return (uint32_t)v;
}

__global__ void quant_fp8(const float* __restrict__ in, uint32_t* __restrict__ out, int n4) {
    int stride = gridDim.x * blockDim.x;
    for (int i = blockIdx.x * blockDim.x + threadIdx.x; i < n4; i += stride) {
        float4 v = reinterpret_cast<const float4*>(in)[i];
        out[i] = pack4_fp8(v.x, v.y, v.z, v.w);
    }
}

// ---------------- MX-fp8 GEMM: C[m][n] = sum_k A[m][k]*B[n][k] ---------------
__device__ __forceinline__ void async16(const void* g, void* l) {
    __builtin_amdgcn_global_load_lds(
        (const __attribute__((address_space(1))) void*)g,
        (__attribute__((address_space(3))) void*)l,
        16, 0, 0);
}

// LDS layout: physical(r, c) holds logical (r, c ^ ((r&7)<<4)); 16B-granular XOR
// keeps global_load_lds chunks intact and staging rows contiguous (rule #21).
__global__ __launch_bounds__(256) void gemm_fp8mx(
    const uint8_t* __restrict__ A,   // [M][K] fp8
    const uint8_t* __restrict__ B,   // [N][K] fp8
    float* __restrict__ C) {         // [M][N] fp32
    __shared__ __align__(16) uint8_t sA[BM * BK];   // 16 KB
    __shared__ __align__(16) uint8_t sB[BN * BK];   // 16 KB

    const int nbn = N_DIM / BN;                  // 32
    const int nwg = (M_DIM / BM) * nbn;          // 2048 (divisible by 8)
    int bid = blockIdx.x;
    int swz = (bid & 7) * (nwg >> 3) + (bid >> 3);   // bijective XCD swizzle
    int bm = (swz / nbn) * BM;
    int bn = (swz % nbn) * BN;

    int tid  = threadIdx.x;
    int lane = tid & 63;
    int wr = (tid >> 7) & 1;   // 2x2 wave grid, 64x64 output per wave
    int wc = (tid >> 6) & 1;

    // staging: thread tid -> logical (row = i*32 + (tid>>3), col 16B chunk), LDS linear tid*16
    int sr = tid >> 3;                 // 0..31
    int sc = (tid & 7) << 4;           // 0..112
    int xc = sc ^ ((sr & 7) << 4);     // pre-swizzled global col (row&7 == sr&7 for all issues)
    const uint8_t* ga = A + (size_t)(bm + sr) * K_DIM + xc;
    const uint8_t* gb = B + (size_t)(bn + sr) * K_DIM + xc;
    uint8_t* la = sA + tid * 16;
    uint8_t* lb = sB + tid * 16;

    // fragment reads: lane holds row (lane&15), K bytes [(lane>>4)*32, +32) as 2x b128
    int fr = lane & 15;
    int xr = (lane & 7) << 4;          // read-side swizzle (r&7 == lane&7: bases are x16)
    int kc = (lane >> 4) << 5;         // 0,32,64,96
    int aoff[2], boff[2];
#pragma unroll
    for (int h = 0; h < 2; ++h) {
        int cs = (kc + (h << 4)) ^ xr;
        aoff[h] = (wr * 64 + fr) * BK + cs;
        boff[h] = (wc * 64 + fr) * BK + cs;
    }

    f32x4 acc[4][4] = {};

    for (int kt = 0; kt < K_DIM; kt += BK) {
#pragma unroll
        for (int i = 0; i < 4; ++i) {
            async16(ga + kt + (size_t)(i * 32) * K_DIM, la + i * 4096);
            async16(gb + kt + (size_t)(i * 32) * K_DIM, lb + i * 4096);
        }
        __syncthreads();   // compiler drains vmcnt(0)+lgkmcnt before s_barrier

        v8i aF[4], bF[4];
#pragma unroll
        for (int m = 0; m < 4; ++m) {
            union { v8i v; i32x4 q[2]; } u;
            u.q[0] = *(const i32x4*)(sA + aoff[0] + m * 16 * BK);
            u.q[1] = *(const i32x4*)(sA + aoff[1] + m * 16 * BK);
            aF[m] = u.v;
        }
#pragma unroll
        for (int n = 0; n < 4; ++n) {
            union { v8i v; i32x4 q[2]; } u;
            u.q[0] = *(const i32x4*)(sB + boff[0] + n * 16 * BK);
            u.q[1] = *(const i32x4*)(sB + boff[1] + n * 16 * BK);
            bF[n] = u.v;
        }
#pragma unroll
        for (int m = 0; m < 4; ++m)
#pragma unroll
            for (int n = 0; n < 4; ++n)
                acc[m][n] = __builtin_amdgcn_mfma_scale_f32_16x16x128_f8f6f4(
                    aF[m], bF[n], acc[m][n],
                    0 /*cbsz: A fp8*/, 0 /*blgp: B fp8*/,
                    0, 0x7F7F7F7F,   // scale_a = 1.0 (e8m0 127) for all blocks
                    0, 0x7F7F7F7F);  // scale_b = 1.0
        __syncthreads();
    }

    // C/D layout (shape-determined, m89/m121-verified): col=lane&15, row=(lane>>4)*4+r
    int cr = bm + wr * 64 + ((lane >> 4) << 2);
    int cc = bn + wc * 64 + (lane & 15);
#pragma unroll
    for (int m = 0; m < 4; ++m)
#pragma unroll
        for (int n = 0; n < 4; ++n)
#pragma unroll
            for (int r = 0; r < 4; ++r)
                C[(size_t)(cr + m * 16 + r) * N_DIM + cc + n * 16] = acc[m][n][r];
}

extern "C" void kernel_launch(void* const* d_in, const int* in_sizes, int n_in,
                              void* d_out, int out_size, void* d_ws, size_t ws_size,
                              hipStream_t stream) {
    const float* x = (const float*)d_in[0];   // [M, K] fp32
    const float* w = (const float*)d_in[1];   // [N, K] fp32
    float* out = (float*)d_out;               // [M, N] fp32

    uint8_t* xq = (uint8_t*)d_ws;                       // M*K fp8
    uint8_t* wq = xq + (size_t)M_DIM * K_DIM;           // N*K fp8  (total 50.3 MB)

    quant_fp8<<<2048, 256, 0, stream>>>(x, (uint32_t*)xq, M_DIM * K_DIM / 4);
    quant_fp8<<<1024, 256, 0, stream>>>(w, (uint32_t*)wq, N_DIM * K_DIM / 4);
    gemm_fp8mx<<<(M_DIM / BM) * (N_DIM / BN), 256, 0, stream>>>(xq, wq, out);
}